// Round 16
// baseline (37.375 us; speedup 1.0000x reference)
//
#include <hip/hip_runtime.h>
#include <hip/hip_bf16.h>
#include <math.h>
#include <stdint.h>

#define BN 2048
#define KF 512
#define OF 512
#define NH 8
#define DD 64

typedef __attribute__((ext_vector_type(8))) short short8;
typedef __attribute__((ext_vector_type(4))) float f32x4;
typedef unsigned short ushortT;

static __device__ __forceinline__ ushortT bfcvt(float f) {
  __hip_bfloat16 h = __float2bfloat16(f);
  return *reinterpret_cast<ushortT*>(&h);
}
static __device__ __forceinline__ float bf2f(ushortT b) {
  return __uint_as_float(((unsigned)b) << 16);
}

#define SPLIT8(vsrc, dhi, dlo)                                        \
  {                                                                   \
    ushortT hi8[8], lo8[8];                                           \
    _Pragma("unroll") for (int i = 0; i < 8; ++i) {                   \
      hi8[i] = bfcvt((vsrc)[i]);                                      \
      lo8[i] = bfcvt((vsrc)[i] - bf2f(hi8[i]));                       \
    }                                                                 \
    (dhi) = *(const int4*)hi8;                                        \
    (dlo) = *(const int4*)lo8;                                        \
  }

// ============ Kernel A: adj pack + split-bf16 GEMM, fragment-major h (R13) ===
__global__ __launch_bounds__(256, 2) void k_main(
    const float* __restrict__ x, const int* __restrict__ adj,
    const float* __restrict__ W, const float* __restrict__ Wb,
    const float* __restrict__ av,
    ushortT* __restrict__ hF, float* __restrict__ E12s, float* __restrict__ E12d,
    uint8_t* __restrict__ adjB) {
  __shared__ __align__(16) uint8_t smem[24576];
  __shared__ float sredS[2][32], sredD[2][32];

  const int t    = threadIdx.x;
  const int hh   = blockIdx.x;
  const int i0   = blockIdx.y * 32;
  const int b    = hh * 64 + blockIdx.y;
  const int lane = t & 63;
  const int wv   = t >> 6;
  const int mt   = wv & 1;
  const int nt   = wv >> 1;
  const int l15  = lane & 15;
  const int lq   = lane >> 4;

  {
    const int gtid = b * 256 + t;
#pragma unroll
    for (int it = 0; it < 4; ++it) {
      const int bidx = gtid + it * (512 * 256);
      const int4 v0 = *(const int4*)(adj + (size_t)bidx * 8);
      const int4 v1 = *(const int4*)(adj + (size_t)bidx * 8 + 4);
      unsigned m = (v0.x ? 1u : 0u) | (v0.y ? 2u : 0u) | (v0.z ? 4u : 0u) | (v0.w ? 8u : 0u)
                 | (v1.x ? 16u : 0u) | (v1.y ? 32u : 0u) | (v1.z ? 64u : 0u) | (v1.w ? 128u : 0u);
      adjB[bidx] = (uint8_t)m;
    }
  }

  ushortT* sAh = (ushortT*)smem;
  ushortT* sAl = sAh + 32 * 64;
  ushortT* sBh = sAl + 32 * 64;
  ushortT* sBl = sBh + 64 * 64;

  f32x4 acc[2] = {};
  const int srow = t >> 3, ss = t & 7;
  int4 aHi, aLo, bHi[2], bLo[2];

  {
    const float* xs = x + (size_t)(i0 + srow) * KF + ss * 8;
    float v[8];
    *(float4*)&v[0] = *(const float4*)xs;
    *(float4*)&v[4] = *(const float4*)(xs + 4);
    SPLIT8(v, aHi, aLo)
#pragma unroll
    for (int rp = 0; rp < 2; ++rp) {
      const int S = t + rp * 256, rw = S >> 3, s2 = S & 7;
      const float* wsrc = W + (size_t)(hh * 64 + rw) * KF + s2 * 8;
      float wv8[8];
      *(float4*)&wv8[0] = *(const float4*)wsrc;
      *(float4*)&wv8[4] = *(const float4*)(wsrc + 4);
      SPLIT8(wv8, bHi[rp], bLo[rp])
    }
  }

  for (int k0 = 0; k0 < 8; ++k0) {
    __syncthreads();
    {
      const int offA = srow * 64 + ((ss ^ (srow & 7)) * 8);
      *(int4*)&sAh[offA] = aHi;
      *(int4*)&sAl[offA] = aLo;
#pragma unroll
      for (int rp = 0; rp < 2; ++rp) {
        const int S = t + rp * 256, rw = S >> 3, s2 = S & 7;
        const int offB = rw * 64 + ((s2 ^ (rw & 7)) * 8);
        *(int4*)&sBh[offB] = bHi[rp];
        *(int4*)&sBl[offB] = bLo[rp];
      }
    }
    __syncthreads();
    if (k0 < 7) {
      const int kc = (k0 + 1) * 64;
      const float* xs = x + (size_t)(i0 + srow) * KF + kc + ss * 8;
      float v[8];
      *(float4*)&v[0] = *(const float4*)xs;
      *(float4*)&v[4] = *(const float4*)(xs + 4);
      SPLIT8(v, aHi, aLo)
#pragma unroll
      for (int rp = 0; rp < 2; ++rp) {
        const int S = t + rp * 256, rw = S >> 3, s2 = S & 7;
        const float* wsrc = W + (size_t)(hh * 64 + rw) * KF + kc + s2 * 8;
        float wv8[8];
        *(float4*)&wv8[0] = *(const float4*)wsrc;
        *(float4*)&wv8[4] = *(const float4*)(wsrc + 4);
        SPLIT8(wv8, bHi[rp], bLo[rp])
      }
    }
#pragma unroll
    for (int kb = 0; kb < 2; ++kb) {
      const int sc = kb * 4 + lq;
      const int arow = mt * 16 + l15;
      const int offA = arow * 64 + ((sc ^ (arow & 7)) * 8);
      const short8 afh = *(const short8*)&sAh[offA];
      const short8 afl = *(const short8*)&sAl[offA];
      const int br0 = nt * 32 + l15;
      const int br1 = br0 + 16;
      const int offB0 = br0 * 64 + ((sc ^ (br0 & 7)) * 8);
      const int offB1 = br1 * 64 + ((sc ^ (br1 & 7)) * 8);
      const short8 bh0 = *(const short8*)&sBh[offB0];
      const short8 bl0 = *(const short8*)&sBl[offB0];
      const short8 bh1 = *(const short8*)&sBh[offB1];
      const short8 bl1 = *(const short8*)&sBl[offB1];
      acc[0] = __builtin_amdgcn_mfma_f32_16x16x32_bf16(afh, bh0, acc[0], 0, 0, 0);
      acc[1] = __builtin_amdgcn_mfma_f32_16x16x32_bf16(afh, bh1, acc[1], 0, 0, 0);
      acc[0] = __builtin_amdgcn_mfma_f32_16x16x32_bf16(afh, bl0, acc[0], 0, 0, 0);
      acc[1] = __builtin_amdgcn_mfma_f32_16x16x32_bf16(afh, bl1, acc[1], 0, 0, 0);
      acc[0] = __builtin_amdgcn_mfma_f32_16x16x32_bf16(afl, bh0, acc[0], 0, 0, 0);
      acc[1] = __builtin_amdgcn_mfma_f32_16x16x32_bf16(afl, bh1, acc[1], 0, 0, 0);
    }
  }

  __syncthreads();
  ushortT* ldsT = (ushortT*)smem;   // [64 d][40]
  float bias2[2], asv[2], adv[2];
#pragma unroll
  for (int bb = 0; bb < 2; ++bb) {
    const int fl = nt * 32 + bb * 16 + l15;
    bias2[bb] = Wb[hh * 64 + fl];
    asv[bb] = av[fl];
    adv[bb] = av[DD + fl];
  }
#pragma unroll
  for (int p = 0; p < 4; ++p) {
    float vs = 0.f, vd = 0.f;
#pragma unroll
    for (int bb = 0; bb < 2; ++bb) {
      const float hv = acc[bb][p] + bias2[bb];
      const ushortT hu = bfcvt(hv);
      vs = fmaf(hv, asv[bb], vs);
      vd = fmaf(hv, adv[bb], vd);
      ldsT[(nt * 32 + bb * 16 + l15) * 40 + mt * 16 + lq * 4 + p] = hu;
    }
    vs += __shfl_xor(vs, 1); vs += __shfl_xor(vs, 2);
    vs += __shfl_xor(vs, 4); vs += __shfl_xor(vs, 8);
    vd += __shfl_xor(vd, 1); vd += __shfl_xor(vd, 2);
    vd += __shfl_xor(vd, 4); vd += __shfl_xor(vd, 8);
    if (l15 == 0) {
      sredS[nt][mt * 16 + lq * 4 + p] = vs;
      sredD[nt][mt * 16 + lq * 4 + p] = vd;
    }
  }
  __syncthreads();
  if (t < 32) {
    const float s1 = sredS[0][t] + sredS[1][t];
    const float s2 = sredD[0][t] + sredD[1][t];
    const size_t gi = (size_t)hh * BN + i0 + t;
    float2 sv; sv.x = __expf(s1); sv.y = __expf(0.2f * s1);
    float2 dv; dv.x = __expf(s2); dv.y = __expf(0.2f * s2);
    *(float2*)&E12s[gi * 2] = sv;
    *(float2*)&E12d[gi * 2] = dv;
  }
  {
    const int n = t >> 6, ln = t & 63;
    const int4 v = *(const int4*)&ldsT[(n * 16 + (ln & 15)) * 40 + ((ln >> 4) * 8)];
    const size_t chunk = (((size_t)hh * 64 + blockIdx.y) * 4 + n) * 64 + ln;
    *(int4*)&hF[chunk * 8] = v;
  }
}

// ============ Kernel B v4: IT=64 (4 row-tiles share each B-fragment) =========
// grid (NH, BN/64) = 256 blocks, 512 threads = 8 waves, 1 block/CU.
// Halves total hF panel traffic (256 blocks x 256KB = 64MB) and doubles
// arithmetic intensity per fragment load.
__global__ __launch_bounds__(512, 2) void k_attn(
    const ushortT* __restrict__ hF, const uint8_t* __restrict__ adjB,
    const float* __restrict__ E12s, const float* __restrict__ E12d,
    float* __restrict__ out) {
  __shared__ __align__(16) float e12[BN * 2];          // 16 KB
  __shared__ __align__(16) float cbuf[4][4 * 16 * 68]; // 69632 B
  __shared__ __align__(16) uint8_t abits[64 * 272];    // 17408 B
  __shared__ float denP[8][4][16];                     // 2 KB

  const int t    = threadIdx.x;
  const int hh   = blockIdx.x;
  const int i0   = blockIdx.y * 64;
  const int lane = t & 63;
  const int wv   = t >> 6;
  const int l15  = lane & 15;
  const int lq   = lane >> 4;

  {
    const float4* g = (const float4*)(E12d + (size_t)hh * BN * 2);
    ((float4*)e12)[t]       = g[t];
    ((float4*)e12)[t + 512] = g[t + 512];
    const int r = t >> 3, pp = t & 7;   // 64 rows x 8 threads x 32B
    const int4* ga = (const int4*)(adjB + (size_t)(i0 + r) * 256 + pp * 32);
    *(int4*)(abits + r * 272 + pp * 32)      = ga[0];
    *(int4*)(abits + r * 272 + pp * 32 + 16) = ga[1];
  }

  float2 ei[4];
#pragma unroll
  for (int tl = 0; tl < 4; ++tl)
    ei[tl] = *(const float2*)&E12s[2 * ((size_t)hh * BN + i0 + tl * 16 + l15)];

  const short8 ones8 = {(short)0x3F80, (short)0x3F80, (short)0x3F80, (short)0x3F80,
                        (short)0x3F80, (short)0x3F80, (short)0x3F80, (short)0x3F80};

  const ushortT* hfb = hF + (size_t)hh * 131072 + (size_t)lane * 8;
  const int lqs = lq * 8;

  __syncthreads();   // e12 + abits staged

  // adjacency words in registers: 4 row-tiles x 8 steps (this wave's 32 bytes)
  unsigned aw[4][8];
#pragma unroll
  for (int tl = 0; tl < 4; ++tl) {
    const uint4 w0 = *(const uint4*)(abits + (tl * 16 + l15) * 272 + wv * 32);
    const uint4 w1 = *(const uint4*)(abits + (tl * 16 + l15) * 272 + wv * 32 + 16);
    aw[tl][0] = w0.x; aw[tl][1] = w0.y; aw[tl][2] = w0.z; aw[tl][3] = w0.w;
    aw[tl][4] = w1.x; aw[tl][5] = w1.y; aw[tl][6] = w1.z; aw[tl][7] = w1.w;
  }

  f32x4 acc[4][4] = {};
  f32x4 accd[4] = {};

  const int jb0 = wv * 8;
  short8 bfA[4], bfB[4];
  {
    const ushortT* b0 = hfb + (size_t)(jb0 * 4) * 512;
#pragma unroll
    for (int n = 0; n < 4; ++n) bfA[n] = *(const short8*)(b0 + (size_t)n * 512);
  }

#define STEP(s, BCUR, BNXT)                                                        \
  {                                                                                \
    if ((s) < 7) {                                                                 \
      const ushortT* bn = hfb + (size_t)((jb0 + (s) + 1) * 4) * 512;               \
      _Pragma("unroll") for (int n = 0; n < 4; ++n)                                \
        BNXT[n] = *(const short8*)(bn + (size_t)n * 512);                          \
    }                                                                              \
    const float* ep = &e12[(((jb0 + (s)) * 32) + lq * 8) * 2];                     \
    const float4 r0 = *(const float4*)(ep);                                        \
    const float4 r1 = *(const float4*)(ep + 4);                                    \
    const float4 r2 = *(const float4*)(ep + 8);                                    \
    const float4 r3 = *(const float4*)(ep + 12);                                   \
    short8 af[4];                                                                  \
    _Pragma("unroll") for (int tl = 0; tl < 4; ++tl) {                             \
      const unsigned bb = (aw[tl][(s)] >> lqs) & 0xffu;                            \
      unsigned pk[4];                                                              \
      _Pragma("unroll") for (int q = 0; q < 4; ++q) {                              \
        const float4 rq = (q == 0) ? r0 : (q == 1) ? r1 : (q == 2) ? r2 : r3;      \
        float wa = fmaxf(ei[tl].x * rq.x, ei[tl].y * rq.y);                        \
        float wb = fmaxf(ei[tl].x * rq.z, ei[tl].y * rq.w);                        \
        wa = ((bb >> (2 * q)) & 1u) ? wa : 0.f;                                    \
        wb = ((bb >> (2 * q + 1)) & 1u) ? wb : 0.f;                                \
        asm("v_cvt_pk_bf16_f32 %0, %1, %2" : "=v"(pk[q]) : "v"(wa), "v"(wb));      \
      }                                                                            \
      af[tl] = *(const short8*)pk;                                                 \
    }                                                                              \
    _Pragma("unroll") for (int n = 0; n < 4; ++n)                                  \
      _Pragma("unroll") for (int tl = 0; tl < 4; ++tl)                             \
        acc[tl][n] = __builtin_amdgcn_mfma_f32_16x16x32_bf16(af[tl], BCUR[n], acc[tl][n], 0, 0, 0); \
    _Pragma("unroll") for (int tl = 0; tl < 4; ++tl)                               \
      accd[tl] = __builtin_amdgcn_mfma_f32_16x16x32_bf16(af[tl], ones8, accd[tl], 0, 0, 0); \
  }

  STEP(0, bfA, bfB) STEP(1, bfB, bfA) STEP(2, bfA, bfB) STEP(3, bfB, bfA)
  STEP(4, bfA, bfB) STEP(5, bfB, bfA) STEP(6, bfA, bfB) STEP(7, bfB, bfA)
#undef STEP

  if (l15 == 0) {
#pragma unroll
    for (int tl = 0; tl < 4; ++tl)
#pragma unroll
      for (int p = 0; p < 4; ++p)
        denP[wv][tl][lq * 4 + p] = accd[tl][p];
  }

#define CWRITE(buf)                                                        \
  _Pragma("unroll") for (int tl = 0; tl < 4; ++tl)                         \
  _Pragma("unroll") for (int n = 0; n < 4; ++n)                            \
  _Pragma("unroll") for (int p = 0; p < 4; ++p)                            \
    (buf)[(tl * 16 + lq * 4 + p) * 68 + n * 16 + l15] = acc[tl][n][p];
#define CADD(buf)                                                          \
  _Pragma("unroll") for (int tl = 0; tl < 4; ++tl)                         \
  _Pragma("unroll") for (int n = 0; n < 4; ++n)                            \
  _Pragma("unroll") for (int p = 0; p < 4; ++p)                            \
    acc[tl][n][p] += (buf)[(tl * 16 + lq * 4 + p) * 68 + n * 16 + l15];

  if (wv >= 4) { CWRITE(cbuf[wv - 4]) }
  __syncthreads();
  if (wv < 4) {
    CADD(cbuf[wv])
    if (wv >= 2) { CWRITE(cbuf[wv]) }
  }
  __syncthreads();
  if (wv < 2) {
    CADD(cbuf[wv + 2])
    if (wv == 1) { CWRITE(cbuf[1]) }
  }
  __syncthreads();
  if (wv == 0) {
    CADD(cbuf[1])
    float dfin[4][4];
#pragma unroll
    for (int tl = 0; tl < 4; ++tl)
#pragma unroll
      for (int p = 0; p < 4; ++p) {
        const int row = lq * 4 + p;
        float d = 0.f;
#pragma unroll
        for (int w = 0; w < 8; ++w) d += denP[w][tl][row];
        dfin[tl][p] = 1.f / d;
      }
#pragma unroll
    for (int tl = 0; tl < 4; ++tl)
#pragma unroll
      for (int n = 0; n < 4; ++n)
#pragma unroll
        for (int p = 0; p < 4; ++p) {
          float v = acc[tl][n][p] * dfin[tl][p];
          v = v > 0.f ? v : expm1f(v);
          out[(size_t)(i0 + tl * 16 + lq * 4 + p) * OF + hh * 64 + n * 16 + l15] = v;
        }
  }
#undef CWRITE
#undef CADD
}

extern "C" void kernel_launch(void* const* d_in, const int* in_sizes, int n_in,
                              void* d_out, int out_size, void* d_ws, size_t ws_size,
                              hipStream_t stream) {
  const float* x  = (const float*)d_in[0];
  const int* adj  = (const int*)d_in[1];
  const float* Ww = (const float*)d_in[2];
  const float* Wb = (const float*)d_in[3];
  const float* a  = (const float*)d_in[4];
  float* outp = (float*)d_out;

  uint8_t* p = (uint8_t*)d_ws;
  ushortT* hF   = (ushortT*)(p + 0x000000);   // 2 MB, fragment-major
  float*   E12d = (float*)  (p + 0x200000);   // 128 KB
  float*   E12s = (float*)  (p + 0x220000);   // 128 KB
  uint8_t* adjB =            p + 0x240000;    // 512 KB

  k_main<<<dim3(NH, BN / 32), 256, 0, stream>>>(x, adj, Ww, Wb, a, hF, E12s, E12d, adjB);
  k_attn<<<dim3(NH, BN / 64), 512, 0, stream>>>(hF, adjB, E12s, E12d, outp);
}